// Round 12
// baseline (964.948 us; speedup 1.0000x reference)
//
#include <hip/hip_runtime.h>

namespace {

constexpr int kB = 64;
constexpr int kL = 4096;
constexpr float kLrW = 1.0f / 64.0f;
constexpr float kLrF = 1.0f / 128.0f;
constexpr float kGradMax = 30.0f;
constexpr float kEps = 1e-9f;
constexpr int kPF = 8;
constexpr int kNC = kL / kPF;          // 512
constexpr int kNP = 28;                // Gram pairs j<t within a chunk

// index of pair (j,t), j<t, in packed triangular order
constexpr int goff(int j, int t) { return 7 * j - (j * (j - 1)) / 2 + (t - j - 1); }

#define DPP_ADD_F32(v, ctrl)                                                   \
    v += __int_as_float(__builtin_amdgcn_update_dpp(                           \
        0, __float_as_int(v), (ctrl), 0xF, 0xF, true))

__device__ __forceinline__ float frcp(float x) { return __builtin_amdgcn_rcpf(x); }
__device__ __forceinline__ float frsq(float x) { return __builtin_amdgcn_rsqf(x); }

// Circular all-reduce within each row of 16: every lane gets its row-16 sum.
__device__ __forceinline__ float rowsum16(float v) {
    DPP_ADD_F32(v, 0x121);  // row_ror:1
    DPP_ADD_F32(v, 0x122);  // row_ror:2
    DPP_ADD_F32(v, 0x124);  // row_ror:4
    DPP_ADD_F32(v, 0x128);  // row_ror:8
    return v;
}

typedef unsigned u32x2v __attribute__((ext_vector_type(2)));

// Row-pair sum (r10-proven): uniform 32-group sum per 32-half.
__device__ __forceinline__ float pairsum16(float v) {
    u32x2v r = __builtin_amdgcn_permlane16_swap(__float_as_uint(v),
                                                __float_as_uint(v),
                                                false, false);
    return __uint_as_float(r[0]) + __uint_as_float(r[1]);
}

// Half-pair sum: v(lane) + v(lane^32), uniform across the wave.
__device__ __forceinline__ float pairsum32(float v) {
    u32x2v r = __builtin_amdgcn_permlane32_swap(__float_as_uint(v),
                                                __float_as_uint(v),
                                                false, false);
    return __uint_as_float(r[0]) + __uint_as_float(r[1]);
}

__device__ __forceinline__ float allsum(float v) {   // full 64-lane sum, uniform
    return pairsum32(pairsum16(rowsum16(v)));
}

typedef const __attribute__((address_space(1))) float gfloat;
typedef __attribute__((address_space(3))) float lfloat;

// ---------- pre-kernel: per (b,chunk) meta block of 128 floats --------------
// [0..7]   su[s] = lrW/(sum|u(s)|^2+eps)
// [8..23]  d half0: dr at 8+s, di at 16+s
// [24..39] d half1: dr at 24+s, di at 32+s
// [40..67] Gr[p]; [68..95] Gi[p]  (G(j,t) = <conj u(j), u(t)>, 28 pairs)
__global__ __launch_bounds__(64, 4) void pre_kernel(
    const float* __restrict__ u_r, const float* __restrict__ u_i,
    const float* __restrict__ x_r, const float* __restrict__ x_i,
    float* __restrict__ meta)
{
    const int lane = threadIdx.x;
    const int bc = blockIdx.x;                 // b*kNC + chunk
    const int b = bc / kNC, chunk = bc % kNC;
    const size_t ub = ((size_t)(b * kL + chunk * kPF)) * 64 + lane;

    float a[kPF], c[kPF];
#pragma unroll
    for (int s = 0; s < kPF; ++s) {
        a[s] = u_r[ub + (size_t)s * 64];
        c[s] = u_i[ub + (size_t)s * 64];
    }
    float e[kPF];
#pragma unroll
    for (int s = 0; s < kPF; ++s) e[s] = allsum(fmaf(a[s], a[s], c[s] * c[s]));

    float gr[kNP], gi[kNP];
#pragma unroll
    for (int j = 0; j < kPF - 1; ++j) {
#pragma unroll
        for (int t = j + 1; t < kPF; ++t) {
            const int p = goff(j, t);
            gr[p] = allsum(fmaf(a[j], a[t], c[j] * c[t]));
            gi[p] = allsum(fmaf(a[j], c[t], -c[j] * a[t]));
        }
    }

    if (lane == 0) {
        float* m = meta + (size_t)bc * 128;
        float buf[96];
#pragma unroll
        for (int s = 0; s < kPF; ++s) buf[s] = kLrW * frcp(e[s] + kEps);
#pragma unroll
        for (int s = 0; s < kPF; ++s) {
            const int t = chunk * kPF + s;
            const float2 xr = *(const float2*)(x_r + ((size_t)b * kL + t) * 2);
            const float2 xi = *(const float2*)(x_i + ((size_t)b * kL + t) * 2);
            buf[8 + s]  = xr.x;  buf[16 + s] = xi.x;   // half 0
            buf[24 + s] = xr.y;  buf[32 + s] = xi.y;   // half 1
        }
#pragma unroll
        for (int p = 0; p < kNP; ++p) { buf[40 + p] = gr[p]; buf[68 + p] = gi[p]; }
#pragma unroll
        for (int q = 0; q < 24; ++q)
            *(float4*)(m + q * 4) = *(float4*)(buf + q * 4);
    }
}

// ---------- main scan kernel ------------------------------------------------
// Per chunk: (1) 8 parallel lookahead reduces <w(t0),u(s)>; (2) serial phase
// with NO reduce on the cycle: v(s) = base[s] (Gram-fixed-up), f-path only.
__global__ __launch_bounds__(64, 1) void adf_kernel(
    const float* __restrict__ u_r, const float* __restrict__ u_i,
    const float* __restrict__ w0r_g, const float* __restrict__ w0i_g,
    const float* __restrict__ f0r_g, const float* __restrict__ f0i_g,
    const float* __restrict__ meta, float* __restrict__ out)
{
    __shared__ float lu[2][kPF][64];
    __shared__ float lq[2][kPF][64];
    __shared__ float lm[2][128];

    const int b = blockIdx.x;
    const int lane = threadIdx.x;
    const int half = lane >> 5;
    const int tap  = lane & 31;

    const int wbase = b * 128 + half * 64 + tap;
    float wAr = w0r_g[wbase],      wAi = w0i_g[wbase];
    float wBr = w0r_g[wbase + 32], wBi = w0i_g[wbase + 32];
    float fr = f0r_g[b * 2 + half];
    float fi = f0i_g[b * 2 + half];
    float psr, psm;
    { const float iv = frsq(fmaf(fr, fr, fi * fi)); psr = fr * iv; psm = -fi * iv; }

    gfloat* gu = (gfloat*)u_r + (size_t)b * kL * 64 + lane * 4;   // width-16 src
    gfloat* gq = (gfloat*)u_i + (size_t)b * kL * 64 + lane * 4;
    gfloat* gm = (gfloat*)meta + (size_t)b * kNC * 128 + lane;
    float2* __restrict__ ob2 = (float2*)out + (size_t)b * kL * 2;

    auto stage = [&](int chunk) {   // exactly 6 vmem ops
        const int par = chunk & 1;
        const size_t ub = (size_t)chunk * 512;
        __builtin_amdgcn_global_load_lds(gu + ub,       (lfloat*)&lu[par][0][0], 16, 0, 0);
        __builtin_amdgcn_global_load_lds(gu + ub + 256, (lfloat*)&lu[par][4][0], 16, 0, 0);
        __builtin_amdgcn_global_load_lds(gq + ub,       (lfloat*)&lq[par][0][0], 16, 0, 0);
        __builtin_amdgcn_global_load_lds(gq + ub + 256, (lfloat*)&lq[par][4][0], 16, 0, 0);
        __builtin_amdgcn_global_load_lds(gm + (size_t)chunk * 128,      (lfloat*)&lm[par][0],  4, 0, 0);
        __builtin_amdgcn_global_load_lds(gm + (size_t)chunk * 128 + 64, (lfloat*)&lm[par][64], 4, 0, 0);
    };

    stage(0);
    stage(1);

    float kR[kPF], kI[kPF];

    for (int c = 0; c < kNC; ++c) {
        const int par = c & 1;
        // stage(c) resident; stage(c+1) stays in flight (in-order vmcnt)
        asm volatile("s_waitcnt vmcnt(6)" ::: "memory");

        // ---- LDS -> registers (36 vector ds_reads, compiler-pipelined) ----
        float2 uu[kPF], uq[kPF];
#pragma unroll
        for (int s = 0; s < kPF; ++s) {
            uu[s] = *(const float2*)&lu[par][s][tap * 2];
            uq[s] = *(const float2*)&lq[par][s][tap * 2];
        }
        float su[kPF], dr[kPF], di[kPF];
        {
            const float4 s0 = *(const float4*)&lm[par][0];
            const float4 s1 = *(const float4*)&lm[par][4];
            su[0]=s0.x; su[1]=s0.y; su[2]=s0.z; su[3]=s0.w;
            su[4]=s1.x; su[5]=s1.y; su[6]=s1.z; su[7]=s1.w;
            const int db = 8 + 16 * half;
            const float4 d0 = *(const float4*)&lm[par][db];
            const float4 d1 = *(const float4*)&lm[par][db + 4];
            const float4 d2 = *(const float4*)&lm[par][db + 8];
            const float4 d3 = *(const float4*)&lm[par][db + 12];
            dr[0]=d0.x; dr[1]=d0.y; dr[2]=d0.z; dr[3]=d0.w;
            dr[4]=d1.x; dr[5]=d1.y; dr[6]=d1.z; dr[7]=d1.w;
            di[0]=d2.x; di[1]=d2.y; di[2]=d2.z; di[3]=d2.w;
            di[4]=d3.x; di[5]=d3.y; di[6]=d3.z; di[7]=d3.w;
        }
        float Gr[kNP], Gi[kNP];
#pragma unroll
        for (int q = 0; q < 7; ++q) {
            const float4 g0 = *(const float4*)&lm[par][40 + q * 4];
            const float4 g1 = *(const float4*)&lm[par][68 + q * 4];
            Gr[q*4]=g0.x; Gr[q*4+1]=g0.y; Gr[q*4+2]=g0.z; Gr[q*4+3]=g0.w;
            Gi[q*4]=g1.x; Gi[q*4+1]=g1.y; Gi[q*4+2]=g1.z; Gi[q*4+3]=g1.w;
        }

        // ---- lookahead: base[s] = <w(t0), u(s)>, 8 independent reduces ----
        float basr[kPF], basi[kPF];
#pragma unroll
        for (int s = 0; s < kPF; ++s) {
            float pr = wAr * uu[s].x;
            pr = fmaf(-wAi, uq[s].x, pr);
            pr = fmaf(wBr, uu[s].y, pr);
            pr = fmaf(-wBi, uq[s].y, pr);
            float pi = wAr * uq[s].x;
            pi = fmaf(wAi, uu[s].x, pi);
            pi = fmaf(wBr, uq[s].y, pi);
            pi = fmaf(wBi, uu[s].y, pi);
            pr = rowsum16(pr); pi = rowsum16(pi);
            basr[s] = pairsum16(pr);
            basi[s] = pairsum16(pi);
        }

        // chunk-entry sdp from carried psi
        float sdpr = su[0] * fmaf(dr[0], psr, -di[0] * psm);
        float sdpi = su[0] * fmaf(dr[0], psm,  di[0] * psr);

        // ---- serial phase: scalar-only cycle ----
#pragma unroll
        for (int s = 0; s < kPF; ++s) {
            const float vr = basr[s], vi = basi[s];
            const float tr = fmaf(-su[s], vr, sdpr);   // tau = su*(d*psi - v)
            const float ti = fmaf(-su[s], vi, sdpi);

            // Gram fixups for remaining steps (s+1 is the only critical one)
#pragma unroll
            for (int j = s + 1; j < kPF; ++j) {
                const int p = goff(s, j);
                basr[j] = fmaf(tr, Gr[p], fmaf(-ti, Gi[p], basr[j]));
                basi[j] = fmaf(tr, Gi[p], fmaf( ti, Gr[p], basi[j]));
            }
            // w accumulation (fills f-path stall slots)
            wAr = fmaf(tr, uu[s].x, fmaf(ti, uq[s].x, wAr));
            wAi = fmaf(ti, uu[s].x, fmaf(-tr, uq[s].x, wAi));
            wBr = fmaf(tr, uu[s].y, fmaf(ti, uq[s].y, wBr));
            wBi = fmaf(ti, uu[s].y, fmaf(-tr, uq[s].y, wBi));

            // f-path (the serial cycle)
            const float kr = fmaf(vr, fr, -vi * fi);
            const float ki = fmaf(vr, fi,  vi * fr);
            kR[s] = kr; kI[s] = ki;
            const float efr = dr[s] - kr, efi = di[s] - ki;
            const float mv2 = fmaf(vr, vr, vi * vi);
            const float ven = pairsum32(mv2) + kEps;
            const float nv = frcp(ven);
            const float Hr = fmaf(efi, vi, efr * vr);        // ef*conj(v)
            const float Hi = fmaf(-efr, vi, efi * vr);
            const float MH = fmaf(Hr, Hr, Hi * Hi);
            const float sc2 = fminf(nv, kGradMax * frsq(MH)); // clip folded
            const float scl = kLrF * sc2;
            fr = fmaf(scl, Hr, fr);                           // f -= lrF*gf
            fi = fmaf(scl, Hi, fi);
            const float iff = frsq(fmaf(fr, fr, fi * fi));
            psr = fr * iff; psm = -fi * iff;
            if (s + 1 < kPF) {
                sdpr = su[s + 1] * fmaf(dr[s + 1], psr, -di[s + 1] * psm);
                sdpi = su[s + 1] * fmaf(dr[s + 1], psm,  di[s + 1] * psr);
            }
        }

        if (tap == 0) {
#pragma unroll
            for (int s = 0; s < kPF; ++s)
                ob2[(size_t)(c * kPF + s) * 2 + half] = make_float2(kR[s], kI[s]);
        }
        // all chunk-c ds_reads have returned before overwriting this parity
        asm volatile("s_waitcnt lgkmcnt(0)" ::: "memory");
        stage((c + 2 < kNC) ? c + 2 : kNC - 1);
    }
}

// ---------- fallback (r7, 838 us, proven) if ws too small -------------------
__global__ __launch_bounds__(64, 1) void adf_fb(
    const float* __restrict__ u_r, const float* __restrict__ u_i,
    const float* __restrict__ x_r, const float* __restrict__ x_i,
    const float* __restrict__ w0r_g, const float* __restrict__ w0i_g,
    const float* __restrict__ f0r_g, const float* __restrict__ f0i_g,
    float* __restrict__ out)
{
    const int b = blockIdx.x;
    const int lane = threadIdx.x;
    const int half = lane >> 5;
    const int tap  = lane & 31;
    const bool lo  = (half == 0);

    const int wbase = b * 128 + half * 64 + tap;
    float wAr = w0r_g[wbase],      wAi = w0i_g[wbase];
    float wBr = w0r_g[wbase + 32], wBi = w0i_g[wbase + 32];

    float fr = f0r_g[b * 2 + half];
    float fi = f0i_g[b * 2 + half];
    const float invf0 = frsq(fmaf(fr, fr, fi * fi));
    float psr = fr * invf0, psm = -fi * invf0;

    const float2* __restrict__ ur2 = (const float2*)u_r + (size_t)b * kL * 32;
    const float2* __restrict__ ui2 = (const float2*)u_i + (size_t)b * kL * 32;
    const float2* __restrict__ xr2 = (const float2*)x_r + (size_t)b * kL;
    const float2* __restrict__ xi2 = (const float2*)x_i + (size_t)b * kL;
    float2* __restrict__ ob2 = (float2*)out + (size_t)b * kL * 2;

    float2 Au[kPF], Aq[kPF], AxR[kPF], AxI[kPF];
    float2 Bu[kPF], Bq[kPF], BxR[kPF], BxI[kPF];
    float suA[kPF], suB[kPF];
    float kR[kPF], kI[kPF];
    float sdpr = 0.0f, sdpi = 0.0f;

    auto loadChunk = [&](float2 (&u)[kPF], float2 (&q)[kPF],
                         float2 (&xR)[kPF], float2 (&xI)[kPF], int chunk) {
#pragma unroll
        for (int s = 0; s < kPF; ++s) {
            int t = chunk * kPF + s;
            t = t < kL ? t : kL - 1;
            u[s]  = ur2[(size_t)t * 32 + tap];
            q[s]  = ui2[(size_t)t * 32 + tap];
            xR[s] = xr2[t];
            xI[s] = xi2[t];
        }
        __builtin_amdgcn_sched_barrier(0);
    };

    auto calcSu = [&](float2 (&u)[kPF], float2 (&q)[kPF], float (&su)[kPF]) {
        float e[kPF];
#pragma unroll
        for (int s = 0; s < kPF; ++s) {
            float t0 = u[s].x * u[s].x;
            t0 = fmaf(u[s].y, u[s].y, t0);
            t0 = fmaf(q[s].x, q[s].x, t0);
            t0 = fmaf(q[s].y, q[s].y, t0);
            e[s] = t0;
        }
#pragma unroll
        for (int s = 0; s < kPF; ++s) { DPP_ADD_F32(e[s], 0x111); }
#pragma unroll
        for (int s = 0; s < kPF; ++s) { DPP_ADD_F32(e[s], 0x112); }
#pragma unroll
        for (int s = 0; s < kPF; ++s) { DPP_ADD_F32(e[s], 0x114); }
#pragma unroll
        for (int s = 0; s < kPF; ++s) { DPP_ADD_F32(e[s], 0x118); }
#pragma unroll
        for (int s = 0; s < kPF; ++s) { DPP_ADD_F32(e[s], 0x142); }
#pragma unroll
        for (int s = 0; s < kPF; ++s)
            su[s] = kLrW * frcp(__int_as_float(
                __builtin_amdgcn_readlane(__float_as_int(e[s]), 31)) + kEps);
    };

    auto body = [&](int s, float2 (&u)[kPF], float2 (&q)[kPF],
                    float2 (&xR)[kPF], float2 (&xI)[kPF], float (&su)[kPF],
                    bool first) {
        const float2 uc = u[s], qc = q[s];
        if (first) {
            const float dr0 = lo ? xR[0].x : xR[0].y;
            const float di0 = lo ? xI[0].x : xI[0].y;
            sdpr = su[0] * fmaf(dr0, psr, -di0 * psm);
            sdpi = su[0] * fmaf(dr0, psm,  di0 * psr);
        }
        float pr = wAr * uc.x;
        pr = fmaf(-wAi, qc.x, pr); pr = fmaf(wBr, uc.y, pr); pr = fmaf(-wBi, qc.y, pr);
        float pi = wAr * qc.x;
        pi = fmaf(wAi, uc.x, pi); pi = fmaf(wBr, qc.y, pi); pi = fmaf(wBi, uc.y, pi);
        DPP_ADD_F32(pr, 0x111); DPP_ADD_F32(pi, 0x111);
        DPP_ADD_F32(pr, 0x112); DPP_ADD_F32(pi, 0x112);
        DPP_ADD_F32(pr, 0x114); DPP_ADD_F32(pi, 0x114);
        DPP_ADD_F32(pr, 0x118); DPP_ADD_F32(pi, 0x118);
        DPP_ADD_F32(pr, 0x142); DPP_ADD_F32(pi, 0x142);
        const float v0r = __int_as_float(__builtin_amdgcn_readlane(__float_as_int(pr), 31));
        const float v1r = __int_as_float(__builtin_amdgcn_readlane(__float_as_int(pr), 63));
        const float v0i = __int_as_float(__builtin_amdgcn_readlane(__float_as_int(pi), 31));
        const float v1i = __int_as_float(__builtin_amdgcn_readlane(__float_as_int(pi), 63));
        const float vr = lo ? v0r : v1r;
        const float vi = lo ? v0i : v1i;

        const float sun = su[s];
        const float tr = fmaf(-sun, vr, sdpr);
        const float ti = fmaf(-sun, vi, sdpi);
        wAr = fmaf(tr, uc.x, fmaf(ti, qc.x, wAr));
        wAi = fmaf(ti, uc.x, fmaf(-tr, qc.x, wAi));
        wBr = fmaf(tr, uc.y, fmaf(ti, qc.y, wBr));
        wBi = fmaf(ti, uc.y, fmaf(-tr, qc.y, wBi));

        const float dr = lo ? xR[s].x : xR[s].y;
        const float di = lo ? xI[s].x : xI[s].y;
        const float kr = fmaf(vr, fr, -vi * fi);
        const float ki = fmaf(vr, fi,  vi * fr);
        kR[s] = kr; kI[s] = ki;
        const float efr = dr - kr, efi = di - ki;
        float ven = v0r * v0r;
        ven = fmaf(v0i, v0i, ven);
        ven = fmaf(v1r, v1r, ven);
        ven = fmaf(v1i, v1i, ven);
        const float nv = frcp(ven + kEps);
        float hr = efr * vr; hr = fmaf(efi, vi, hr);
        float hi = efi * vr; hi = fmaf(-efr, vi, hi);
        hr *= nv; hi *= nv;
        float mg = hr * hr; mg = fmaf(hi, hi, mg);
        const float sc = fminf(1.0f, kGradMax * frsq(mg));
        const float scl = kLrF * sc;
        fr = fmaf(scl, hr, fr);
        fi = fmaf(scl, hi, fi);
        const float invf = frsq(fmaf(fr, fr, fi * fi));
        psr = fr * invf; psm = -fi * invf;
        if (s + 1 < kPF) {
            const float dnr = lo ? xR[s + 1].x : xR[s + 1].y;
            const float dni = lo ? xI[s + 1].x : xI[s + 1].y;
            sdpr = su[s + 1] * fmaf(dnr, psr, -dni * psm);
            sdpi = su[s + 1] * fmaf(dnr, psm,  dni * psr);
        }
    };

    auto processChunk = [&](int tbase, float2 (&u)[kPF], float2 (&q)[kPF],
                            float2 (&xR)[kPF], float2 (&xI)[kPF], float (&su)[kPF]) {
#pragma unroll
        for (int s = 0; s < kPF; ++s)
            body(s, u, q, xR, xI, su, s == 0);
        if (tap == 0) {
#pragma unroll
            for (int s = 0; s < kPF; ++s)
                ob2[(size_t)(tbase + s) * 2 + half] = make_float2(kR[s], kI[s]);
        }
    };

    loadChunk(Au, Aq, AxR, AxI, 0);
    loadChunk(Bu, Bq, BxR, BxI, 1);
    calcSu(Au, Aq, suA);

    for (int c = 0; c < kNC; c += 2) {
        processChunk(c * kPF, Au, Aq, AxR, AxI, suA);
        loadChunk(Au, Aq, AxR, AxI, (c + 2 < kNC) ? c + 2 : kNC - 1);
        calcSu(Bu, Bq, suB);
        processChunk((c + 1) * kPF, Bu, Bq, BxR, BxI, suB);
        loadChunk(Bu, Bq, BxR, BxI, (c + 3 < kNC) ? c + 3 : kNC - 1);
        calcSu(Au, Aq, suA);
    }
}

} // namespace

extern "C" void kernel_launch(void* const* d_in, const int* in_sizes, int n_in,
                              void* d_out, int out_size, void* d_ws, size_t ws_size,
                              hipStream_t stream) {
    const float* u_r  = (const float*)d_in[0];
    const float* u_i  = (const float*)d_in[1];
    const float* x_r  = (const float*)d_in[2];
    const float* x_i  = (const float*)d_in[3];
    const float* w0_r = (const float*)d_in[4];
    const float* w0_i = (const float*)d_in[5];
    const float* f0_r = (const float*)d_in[6];
    const float* f0_i = (const float*)d_in[7];
    float* out = (float*)d_out;

    const size_t need = (size_t)kB * kNC * 128 * sizeof(float);   // 16 MB meta
    if (ws_size >= need) {
        float* meta = (float*)d_ws;
        pre_kernel<<<dim3(kB * kNC), dim3(64), 0, stream>>>(u_r, u_i, x_r, x_i, meta);
        adf_kernel<<<dim3(kB), dim3(64), 0, stream>>>(
            u_r, u_i, w0_r, w0_i, f0_r, f0_i, meta, out);
    } else {
        adf_fb<<<dim3(kB), dim3(64), 0, stream>>>(
            u_r, u_i, x_r, x_i, w0_r, w0_i, f0_r, f0_i, out);
    }
}

// Round 13
// 714.862 us; speedup vs baseline: 1.3498x; 1.3498x over previous
//
#include <hip/hip_runtime.h>

namespace {

constexpr int kB = 64;
constexpr int kL = 4096;
constexpr float kLrW = 1.0f / 64.0f;
constexpr float kLrF = 1.0f / 128.0f;
constexpr float kGradMax = 30.0f;
constexpr float kEps = 1e-9f;
constexpr int kPF = 8;
constexpr int kNC = kL / kPF;

#define DPP_ADD_F32(v, ctrl)                                                   \
    v += __int_as_float(__builtin_amdgcn_update_dpp(                           \
        0, __float_as_int(v), (ctrl), 0xF, 0xF, true))

__device__ __forceinline__ float rl(float v, int l) {
    return __int_as_float(__builtin_amdgcn_readlane(__float_as_int(v), l));
}
__device__ __forceinline__ float frcp(float x) { return __builtin_amdgcn_rcpf(x); }
__device__ __forceinline__ float frsq(float x) { return __builtin_amdgcn_rsqf(x); }

// ---------------- packed-f32 complex primitives (VOP3P) --------------------
// float2 = (re, im) in an aligned VGPR pair. Derivations:
//  a += s*u:  step1 lo: -s.hi*u.hi  hi: s.hi*u.lo   step2: +s.lo*(u.lo,u.hi)
__device__ __forceinline__ void cfma(float2& a, const float2 s, const float2 u) {
    asm("v_pk_fma_f32 %0, %1, %2, %0 op_sel:[1,1,0] op_sel_hi:[1,0,1] neg_lo:[0,1,0]\n\t"
        "v_pk_fma_f32 %0, %1, %2, %0 op_sel:[0,0,0] op_sel_hi:[0,1,1]"
        : "+v"(a) : "v"(s), "v"(u));
}
//  a += s*conj(u): step1 lo: s.hi*u.hi  hi: s.hi*u.lo  step2: s.lo*(u.lo,-u.hi)
__device__ __forceinline__ void cfma_conj(float2& a, const float2 s, const float2 u) {
    asm("v_pk_fma_f32 %0, %1, %2, %0 op_sel:[1,1,0] op_sel_hi:[1,0,1]\n\t"
        "v_pk_fma_f32 %0, %1, %2, %0 op_sel:[0,0,0] op_sel_hi:[0,1,1] neg_hi:[0,1,0]"
        : "+v"(a) : "v"(s), "v"(u));
}
//  r = s*u
__device__ __forceinline__ float2 cmul(const float2 s, const float2 u) {
    float2 r;
    asm("v_pk_mul_f32 %0, %1, %2 op_sel:[1,1] op_sel_hi:[1,0] neg_lo:[0,1]\n\t"
        "v_pk_fma_f32 %0, %1, %2, %0 op_sel:[0,0,0] op_sel_hi:[0,1,1]"
        : "=&v"(r) : "v"(s), "v"(u));
    return r;
}
//  r = s*conj(u):  re = s.lo*u.lo + s.hi*u.hi ; im = s.hi*u.lo - s.lo*u.hi
__device__ __forceinline__ float2 cmul_conj(const float2 s, const float2 u) {
    float2 r;
    asm("v_pk_mul_f32 %0, %1, %2 op_sel:[1,1] op_sel_hi:[1,0]\n\t"
        "v_pk_fma_f32 %0, %1, %2, %0 op_sel:[0,0,0] op_sel_hi:[0,1,1] neg_hi:[0,1,0]"
        : "=&v"(r) : "v"(s), "v"(u));
    return r;
}
//  r = c - s*u (per-lane)
__device__ __forceinline__ float2 pk_fnma(const float2 s, const float2 u, const float2 c) {
    float2 r;
    asm("v_pk_fma_f32 %0, %1, %2, %3 neg_lo:[1,0,0] neg_hi:[1,0,0]"
        : "=v"(r) : "v"(s), "v"(u), "v"(c));
    return r;
}
//  r = a - b (per-lane)
__device__ __forceinline__ float2 pk_sub(const float2 a, const float2 b) {
    float2 r;
    asm("v_pk_add_f32 %0, %1, %2 neg_lo:[0,1] neg_hi:[0,1]" : "=v"(r) : "v"(a), "v"(b));
    return r;
}
//  r = a * b (per-lane)
__device__ __forceinline__ float2 pk_mul(const float2 a, const float2 b) {
    float2 r;
    asm("v_pk_mul_f32 %0, %1, %2" : "=v"(r) : "v"(a), "v"(b));
    return r;
}

typedef unsigned u32x2v __attribute__((ext_vector_type(2)));
__device__ __forceinline__ float pairsum16(float v) {
    u32x2v r = __builtin_amdgcn_permlane16_swap(__float_as_uint(v),
                                                __float_as_uint(v), false, false);
    return __uint_as_float(r[0]) + __uint_as_float(r[1]);
}
__device__ __forceinline__ float pairsum32(float v) {
    u32x2v r = __builtin_amdgcn_permlane32_swap(__float_as_uint(v),
                                                __float_as_uint(v), false, false);
    return __uint_as_float(r[0]) + __uint_as_float(r[1]);
}
__device__ __forceinline__ float rowsum16(float v) {
    DPP_ADD_F32(v, 0x121); DPP_ADD_F32(v, 0x122);
    DPP_ADD_F32(v, 0x124); DPP_ADD_F32(v, 0x128);
    return v;
}

// ---------- pre-kernel (r10-proven): meta[b,t][8]={su,su,d0r,d0i,d1r,d1i,0,0}
__global__ __launch_bounds__(256, 1) void pre_kernel(
    const float* __restrict__ u_r, const float* __restrict__ u_i,
    const float* __restrict__ x_r, const float* __restrict__ x_i,
    float* __restrict__ meta)
{
    const int lane = threadIdx.x & 63;
    const int idx = blockIdx.x * 4 + (threadIdx.x >> 6);   // flat b*L + t
    const float a = u_r[(size_t)idx * 64 + lane];
    const float c = u_i[(size_t)idx * 64 + lane];
    float e = fmaf(a, a, c * c);
    e = rowsum16(e);
    e = pairsum16(e);
    e = pairsum32(e);
    if (lane == 0) {
        const float su = kLrW * frcp(e + kEps);
        const float2 xr = *(const float2*)(x_r + (size_t)idx * 2);
        const float2 xi = *(const float2*)(x_i + (size_t)idx * 2);
        float4* m = (float4*)(meta + (size_t)idx * 8);
        m[0] = make_float4(su, su, xr.x, xi.x);
        m[1] = make_float4(xr.y, xi.y, 0.0f, 0.0f);
    }
}

// ---------- main scan kernel: r7 skeleton + packed math ---------------------
__global__ __launch_bounds__(64, 1) void adf_kernel(
    const float* __restrict__ u_r, const float* __restrict__ u_i,
    const float* __restrict__ w0r_g, const float* __restrict__ w0i_g,
    const float* __restrict__ f0r_g, const float* __restrict__ f0i_g,
    const float* __restrict__ meta, float* __restrict__ out)
{
    const int b = blockIdx.x;
    const int lane = threadIdx.x;
    const int half = lane >> 5;
    const int tap  = lane & 31;

    const int wbase = b * 128 + half * 64 + tap;
    float2 wA = make_float2(w0r_g[wbase],      w0i_g[wbase]);
    float2 wB = make_float2(w0r_g[wbase + 32], w0i_g[wbase + 32]);

    float2 f2 = make_float2(f0r_g[b * 2 + half], f0i_g[b * 2 + half]);
    float2 psi2;
    {
        const float iv = frsq(fmaf(f2.x, f2.x, f2.y * f2.y));
        psi2 = make_float2(f2.x * iv, -f2.y * iv);
    }

    const float2* __restrict__ ur2 = (const float2*)u_r + (size_t)b * kL * 32;
    const float2* __restrict__ ui2 = (const float2*)u_i + (size_t)b * kL * 32;
    const float* __restrict__ mp = meta + (size_t)b * kL * 8;
    float2* __restrict__ ob2 = (float2*)out + (size_t)b * kL * 2;

    float2 Au[kPF], Aq[kPF], Asu[kPF], Ad[kPF];
    float2 Bu[kPF], Bq[kPF], Bsu[kPF], Bd[kPF];
    float2 kO[kPF];
    float2 sdp2 = make_float2(0.f, 0.f);

    auto loadChunk = [&](float2 (&u)[kPF], float2 (&q)[kPF],
                         float2 (&su)[kPF], float2 (&d)[kPF], int chunk) {
#pragma unroll
        for (int s = 0; s < kPF; ++s) {
            int t = chunk * kPF + s;
            t = t < kL ? t : kL - 1;
            u[s]  = ur2[(size_t)t * 32 + tap];
            q[s]  = ui2[(size_t)t * 32 + tap];
            su[s] = *(const float2*)(mp + (size_t)t * 8);                  // (su,su)
            d[s]  = *(const float2*)(mp + (size_t)t * 8 + 2 + 2 * half);   // (dr,di)
        }
        __builtin_amdgcn_sched_barrier(0);   // keep prefetch ahead of compute (r7)
    };

    auto body = [&](int s, float2 (&u)[kPF], float2 (&q)[kPF],
                    float2 (&su)[kPF], float2 (&d)[kPF], bool first) {
        // repack complex operands (re,im) from split arrays
        const float2 cA = make_float2(u[s].x, q[s].x);
        const float2 cB = make_float2(u[s].y, q[s].y);
        if (first) {   // chunk-entry sdp from carried psi
            sdp2 = pk_mul(su[0], cmul(d[0], psi2));
        }
        // dot partials (packed) + 5-level DPP reduce + readlane broadcast (r7)
        float2 p = cmul(wA, cA);
        cfma(p, wB, cB);
        float pr = p.x, pi = p.y;
        DPP_ADD_F32(pr, 0x111); DPP_ADD_F32(pi, 0x111);
        DPP_ADD_F32(pr, 0x112); DPP_ADD_F32(pi, 0x112);
        DPP_ADD_F32(pr, 0x114); DPP_ADD_F32(pi, 0x114);
        DPP_ADD_F32(pr, 0x118); DPP_ADD_F32(pi, 0x118);
        DPP_ADD_F32(pr, 0x142); DPP_ADD_F32(pi, 0x142);
        const float v0r = rl(pr, 31), v1r = rl(pr, 63);
        const float v0i = rl(pi, 31), v1i = rl(pi, 63);
        const float2 v2 = make_float2(half ? v1r : v0r, half ? v1i : v0i);

        // tau = sdp - su*v ; w += tau*conj(u)
        const float2 tau = pk_fnma(su[s], v2, sdp2);
        cfma_conj(wA, tau, cA);
        cfma_conj(wB, tau, cB);

        // f-path
        const float2 k2 = cmul(v2, f2);            // k = v*f (pre-update f)
        kO[s] = k2;
        const float2 ef = pk_sub(d[s], k2);        // e_f = d - k
        float ven = v0r * v0r;
        ven = fmaf(v0i, v0i, ven);
        ven = fmaf(v1r, v1r, ven);
        ven = fmaf(v1i, v1i, ven);
        const float nv = frcp(ven + kEps);
        const float2 H = cmul_conj(ef, v2);        // ef*conj(v)
        const float MH = fmaf(H.x, H.x, H.y * H.y);
        const float sc = fminf(nv, kGradMax * frsq(MH));   // norm+clip folded
        const float scl = kLrF * sc;
        f2.x = fmaf(scl, H.x, f2.x);               // f -= lrF*gf
        f2.y = fmaf(scl, H.y, f2.y);
        const float iff = frsq(fmaf(f2.x, f2.x, f2.y * f2.y));
        psi2 = make_float2(f2.x * iff, -f2.y * iff);
        if (s + 1 < kPF) {
            sdp2 = pk_mul(su[s + 1], cmul(d[s + 1], psi2));
        }
    };

    auto processChunk = [&](int tbase, float2 (&u)[kPF], float2 (&q)[kPF],
                            float2 (&su)[kPF], float2 (&d)[kPF]) {
#pragma unroll
        for (int s = 0; s < kPF; ++s)
            body(s, u, q, su, d, s == 0);
        if (tap == 0) {
#pragma unroll
            for (int s = 0; s < kPF; ++s)
                ob2[(size_t)(tbase + s) * 2 + half] = kO[s];
        }
    };

    loadChunk(Au, Aq, Asu, Ad, 0);
    loadChunk(Bu, Bq, Bsu, Bd, 1);

    for (int c = 0; c < kNC; c += 2) {
        processChunk(c * kPF, Au, Aq, Asu, Ad);
        loadChunk(Au, Aq, Asu, Ad, (c + 2 < kNC) ? c + 2 : kNC - 1);
        processChunk((c + 1) * kPF, Bu, Bq, Bsu, Bd);
        loadChunk(Bu, Bq, Bsu, Bd, (c + 3 < kNC) ? c + 3 : kNC - 1);
    }
}

// ---------- fallback (r7, 838 us, proven) if ws too small -------------------
__global__ __launch_bounds__(64, 1) void adf_fb(
    const float* __restrict__ u_r, const float* __restrict__ u_i,
    const float* __restrict__ x_r, const float* __restrict__ x_i,
    const float* __restrict__ w0r_g, const float* __restrict__ w0i_g,
    const float* __restrict__ f0r_g, const float* __restrict__ f0i_g,
    float* __restrict__ out)
{
    const int b = blockIdx.x;
    const int lane = threadIdx.x;
    const int half = lane >> 5;
    const int tap  = lane & 31;
    const bool lo  = (half == 0);

    const int wbase = b * 128 + half * 64 + tap;
    float wAr = w0r_g[wbase],      wAi = w0i_g[wbase];
    float wBr = w0r_g[wbase + 32], wBi = w0i_g[wbase + 32];

    float fr = f0r_g[b * 2 + half];
    float fi = f0i_g[b * 2 + half];
    const float invf0 = frsq(fmaf(fr, fr, fi * fi));
    float psr = fr * invf0, psm = -fi * invf0;

    const float2* __restrict__ ur2 = (const float2*)u_r + (size_t)b * kL * 32;
    const float2* __restrict__ ui2 = (const float2*)u_i + (size_t)b * kL * 32;
    const float2* __restrict__ xr2 = (const float2*)x_r + (size_t)b * kL;
    const float2* __restrict__ xi2 = (const float2*)x_i + (size_t)b * kL;
    float2* __restrict__ ob2 = (float2*)out + (size_t)b * kL * 2;

    float2 Au[kPF], Aq[kPF], AxR[kPF], AxI[kPF];
    float2 Bu[kPF], Bq[kPF], BxR[kPF], BxI[kPF];
    float suA[kPF], suB[kPF];
    float kR[kPF], kI[kPF];
    float sdpr = 0.0f, sdpi = 0.0f;

    auto loadChunk = [&](float2 (&u)[kPF], float2 (&q)[kPF],
                         float2 (&xR)[kPF], float2 (&xI)[kPF], int chunk) {
#pragma unroll
        for (int s = 0; s < kPF; ++s) {
            int t = chunk * kPF + s;
            t = t < kL ? t : kL - 1;
            u[s]  = ur2[(size_t)t * 32 + tap];
            q[s]  = ui2[(size_t)t * 32 + tap];
            xR[s] = xr2[t];
            xI[s] = xi2[t];
        }
        __builtin_amdgcn_sched_barrier(0);
    };

    auto calcSu = [&](float2 (&u)[kPF], float2 (&q)[kPF], float (&su)[kPF]) {
        float e[kPF];
#pragma unroll
        for (int s = 0; s < kPF; ++s) {
            float t0 = u[s].x * u[s].x;
            t0 = fmaf(u[s].y, u[s].y, t0);
            t0 = fmaf(q[s].x, q[s].x, t0);
            t0 = fmaf(q[s].y, q[s].y, t0);
            e[s] = t0;
        }
#pragma unroll
        for (int s = 0; s < kPF; ++s) { DPP_ADD_F32(e[s], 0x111); }
#pragma unroll
        for (int s = 0; s < kPF; ++s) { DPP_ADD_F32(e[s], 0x112); }
#pragma unroll
        for (int s = 0; s < kPF; ++s) { DPP_ADD_F32(e[s], 0x114); }
#pragma unroll
        for (int s = 0; s < kPF; ++s) { DPP_ADD_F32(e[s], 0x118); }
#pragma unroll
        for (int s = 0; s < kPF; ++s) { DPP_ADD_F32(e[s], 0x142); }
#pragma unroll
        for (int s = 0; s < kPF; ++s) su[s] = kLrW * frcp(rl(e[s], 31) + kEps);
    };

    auto body = [&](int s, float2 (&u)[kPF], float2 (&q)[kPF],
                    float2 (&xR)[kPF], float2 (&xI)[kPF], float (&su)[kPF],
                    bool first) {
        const float2 uc = u[s], qc = q[s];
        if (first) {
            const float dr0 = lo ? xR[0].x : xR[0].y;
            const float di0 = lo ? xI[0].x : xI[0].y;
            sdpr = su[0] * fmaf(dr0, psr, -di0 * psm);
            sdpi = su[0] * fmaf(dr0, psm,  di0 * psr);
        }
        float pr = wAr * uc.x;
        pr = fmaf(-wAi, qc.x, pr); pr = fmaf(wBr, uc.y, pr); pr = fmaf(-wBi, qc.y, pr);
        float pi = wAr * qc.x;
        pi = fmaf(wAi, uc.x, pi); pi = fmaf(wBr, qc.y, pi); pi = fmaf(wBi, uc.y, pi);
        DPP_ADD_F32(pr, 0x111); DPP_ADD_F32(pi, 0x111);
        DPP_ADD_F32(pr, 0x112); DPP_ADD_F32(pi, 0x112);
        DPP_ADD_F32(pr, 0x114); DPP_ADD_F32(pi, 0x114);
        DPP_ADD_F32(pr, 0x118); DPP_ADD_F32(pi, 0x118);
        DPP_ADD_F32(pr, 0x142); DPP_ADD_F32(pi, 0x142);
        const float v0r = rl(pr, 31), v1r = rl(pr, 63);
        const float v0i = rl(pi, 31), v1i = rl(pi, 63);
        const float vr = lo ? v0r : v1r;
        const float vi = lo ? v0i : v1i;

        const float sun = su[s];
        const float tr = fmaf(-sun, vr, sdpr);
        const float ti = fmaf(-sun, vi, sdpi);
        wAr = fmaf(tr, uc.x, fmaf(ti, qc.x, wAr));
        wAi = fmaf(ti, uc.x, fmaf(-tr, qc.x, wAi));
        wBr = fmaf(tr, uc.y, fmaf(ti, qc.y, wBr));
        wBi = fmaf(ti, uc.y, fmaf(-tr, qc.y, wBi));

        const float dr = lo ? xR[s].x : xR[s].y;
        const float di = lo ? xI[s].x : xI[s].y;
        const float kr = fmaf(vr, fr, -vi * fi);
        const float ki = fmaf(vr, fi,  vi * fr);
        kR[s] = kr; kI[s] = ki;
        const float efr = dr - kr, efi = di - ki;
        float ven = v0r * v0r;
        ven = fmaf(v0i, v0i, ven);
        ven = fmaf(v1r, v1r, ven);
        ven = fmaf(v1i, v1i, ven);
        const float nv = frcp(ven + kEps);
        float hr = efr * vr; hr = fmaf(efi, vi, hr);
        float hi = efi * vr; hi = fmaf(-efr, vi, hi);
        hr *= nv; hi *= nv;
        float mg = hr * hr; mg = fmaf(hi, hi, mg);
        const float sc = fminf(1.0f, kGradMax * frsq(mg));
        const float scl = kLrF * sc;
        fr = fmaf(scl, hr, fr);
        fi = fmaf(scl, hi, fi);
        const float invf = frsq(fmaf(fr, fr, fi * fi));
        psr = fr * invf; psm = -fi * invf;
        if (s + 1 < kPF) {
            const float dnr = lo ? xR[s + 1].x : xR[s + 1].y;
            const float dni = lo ? xI[s + 1].x : xI[s + 1].y;
            sdpr = su[s + 1] * fmaf(dnr, psr, -dni * psm);
            sdpi = su[s + 1] * fmaf(dnr, psm,  dni * psr);
        }
    };

    auto processChunk = [&](int tbase, float2 (&u)[kPF], float2 (&q)[kPF],
                            float2 (&xR)[kPF], float2 (&xI)[kPF], float (&su)[kPF]) {
#pragma unroll
        for (int s = 0; s < kPF; ++s)
            body(s, u, q, xR, xI, su, s == 0);
        if (tap == 0) {
#pragma unroll
            for (int s = 0; s < kPF; ++s)
                ob2[(size_t)(tbase + s) * 2 + half] = make_float2(kR[s], kI[s]);
        }
    };

    loadChunk(Au, Aq, AxR, AxI, 0);
    loadChunk(Bu, Bq, BxR, BxI, 1);
    calcSu(Au, Aq, suA);

    for (int c = 0; c < kNC; c += 2) {
        processChunk(c * kPF, Au, Aq, AxR, AxI, suA);
        loadChunk(Au, Aq, AxR, AxI, (c + 2 < kNC) ? c + 2 : kNC - 1);
        calcSu(Bu, Bq, suB);
        processChunk((c + 1) * kPF, Bu, Bq, BxR, BxI, suB);
        loadChunk(Bu, Bq, BxR, BxI, (c + 3 < kNC) ? c + 3 : kNC - 1);
        calcSu(Au, Aq, suA);
    }
}

} // namespace

extern "C" void kernel_launch(void* const* d_in, const int* in_sizes, int n_in,
                              void* d_out, int out_size, void* d_ws, size_t ws_size,
                              hipStream_t stream) {
    const float* u_r  = (const float*)d_in[0];
    const float* u_i  = (const float*)d_in[1];
    const float* x_r  = (const float*)d_in[2];
    const float* x_i  = (const float*)d_in[3];
    const float* w0_r = (const float*)d_in[4];
    const float* w0_i = (const float*)d_in[5];
    const float* f0_r = (const float*)d_in[6];
    const float* f0_i = (const float*)d_in[7];
    float* out = (float*)d_out;

    const size_t need = (size_t)kB * kL * 8 * sizeof(float);   // 8 MB meta
    if (ws_size >= need) {
        float* meta = (float*)d_ws;
        pre_kernel<<<dim3(kB * kL / 4), dim3(256), 0, stream>>>(u_r, u_i, x_r, x_i, meta);
        adf_kernel<<<dim3(kB), dim3(64), 0, stream>>>(
            u_r, u_i, w0_r, w0_i, f0_r, f0_i, meta, out);
    } else {
        adf_fb<<<dim3(kB), dim3(64), 0, stream>>>(
            u_r, u_i, x_r, x_i, w0_r, w0_i, f0_r, f0_i, out);
    }
}